// Round 13
// baseline (202.624 us; speedup 1.0000x reference)
//
#include <hip/hip_runtime.h>

// Round 10 (resubmit — GPUAcquisitionTimeout, never ran):
// nontemporal gathers. r9 result: coop idx fetch 62->59us (-5%,
// not the predicted -25%) -> coalesced lanes are near-free; only DIVERGENT
// lanes pay. Wall arithmetic: 2M edges x 256B / 16B-per-lane = 32M divergent
// lane-loads / (256CU x 2.4GHz x ~1/cy) = 52us; measured 59 = 113%.
// Last untested mechanism consistent with ALL nulls (L2-residency, ILP,
// lane-halving, launch-rate, idx-redundancy): L1 allocation/fill
// serialization — every gather is an L1 miss (12.8MB table vs 32KB L1),
// 2 x 64B fills/row, measured 0.53 fills/cy/CU ~= a 2-cy fill pipe limit.
// Test: __builtin_nontemporal_load (no L1 allocate) on the 4 row gathers.
// Decision rule: edge < 55 confirms L1-fill model; >= 58 -> 6th null ->
// declare divergent-gather floor (ROOFLINE) next round.

#define FD 64

__device__ __forceinline__ int q8pack(float v0, float v1, float v2, float v3, float inv) {
    float a0 = fminf(fmaxf(v0 * inv, -127.f), 127.f);
    float a1 = fminf(fmaxf(v1 * inv, -127.f), 127.f);
    float a2 = fminf(fmaxf(v2 * inv, -127.f), 127.f);
    float a3 = fminf(fmaxf(v3 * inv, -127.f), 127.f);
    int q0 = ((int)rintf(a0)) & 0xff;
    int q1 = ((int)rintf(a1)) & 0xff;
    int q2 = ((int)rintf(a2)) & 0xff;
    int q3 = ((int)rintf(a3)) & 0xff;
    return q0 | (q1 << 8) | (q2 << 16) | (q3 << 24);
}

// 8 lanes per node. Lane l holds dims [8l, 8l+8) of x (2 float4) and of h
// (2 float4); writes one int4 (16 int8) -> row = 8 lanes x 16 B = 128 B.
__global__ __launch_bounds__(256, 8)
void pack_kernel(const float4* __restrict__ xd, const float4* __restrict__ hd,
                 const float4* __restrict__ xg, const float4* __restrict__ hg,
                 int4* __restrict__ fd, int4* __restrict__ fg,
                 float* __restrict__ sd, float* __restrict__ sg,
                 int n_d, int n_g)
{
    int tid  = (int)(blockIdx.x * blockDim.x + threadIdx.x);
    int node = tid >> 3;
    int lane = threadIdx.x & 7;
    int total = n_d + n_g;
    if (node >= total) return;

    const float4* x; const float4* h; int4* o; float* s; int n;
    if (node < n_d) { x = xd; h = hd; o = fd; s = sd; n = node; }
    else            { x = xg; h = hg; o = fg; s = sg; n = node - n_d; }

    float4 a0 = x[(size_t)n * 16 + lane * 2];
    float4 a1 = x[(size_t)n * 16 + lane * 2 + 1];
    float4 b0 = h[(size_t)n * 16 + lane * 2];
    float4 b1 = h[(size_t)n * 16 + lane * 2 + 1];

    float ss = a0.x*a0.x + a0.y*a0.y + a0.z*a0.z + a0.w*a0.w
             + a1.x*a1.x + a1.y*a1.y + a1.z*a1.z + a1.w*a1.w
             + b0.x*b0.x + b0.y*b0.y + b0.z*b0.z + b0.w*b0.w
             + b1.x*b1.x + b1.y*b1.y + b1.z*b1.z + b1.w*b1.w;
    #pragma unroll
    for (int m = 4; m >= 1; m >>= 1) ss += __shfl_xor(ss, m);
    float r = rsqrtf(ss);

    a0.x *= r; a0.y *= r; a0.z *= r; a0.w *= r;
    a1.x *= r; a1.y *= r; a1.z *= r; a1.w *= r;
    b0.x *= r; b0.y *= r; b0.z *= r; b0.w *= r;
    b1.x *= r; b1.y *= r; b1.z *= r; b1.w *= r;

    float mx = fmaxf(
        fmaxf(fmaxf(fmaxf(fabsf(a0.x), fabsf(a0.y)), fmaxf(fabsf(a0.z), fabsf(a0.w))),
              fmaxf(fmaxf(fabsf(a1.x), fabsf(a1.y)), fmaxf(fabsf(a1.z), fabsf(a1.w)))),
        fmaxf(fmaxf(fmaxf(fabsf(b0.x), fabsf(b0.y)), fmaxf(fabsf(b0.z), fabsf(b0.w))),
              fmaxf(fmaxf(fabsf(b1.x), fabsf(b1.y)), fmaxf(fabsf(b1.z), fabsf(b1.w)))));
    #pragma unroll
    for (int m = 4; m >= 1; m >>= 1) mx = fmaxf(mx, __shfl_xor(mx, m));

    float inv = 127.0f / mx;

    int4 w;
    w.x = q8pack(a0.x, a0.y, a0.z, a0.w, inv);
    w.y = q8pack(a1.x, a1.y, a1.z, a1.w, inv);
    w.z = q8pack(b0.x, b0.y, b0.z, b0.w, inv);
    w.w = q8pack(b1.x, b1.y, b1.z, b1.w, inv);
    o[(size_t)n * 8 + lane] = w;

    if (lane == 0) s[n] = mx * (1.0f / 127.0f);
}

__device__ __forceinline__ int dot4(int a, int b, int c) {
    return __builtin_amdgcn_sdot4(a, b, c, false);   // v_dot4_i32_i8
}

// Nontemporal 16B load: no L1 allocation for one-touch gather rows.
__device__ __forceinline__ int4 ntload(const int4* p) {
    typedef int v4 __attribute__((ext_vector_type(4)));
    v4 v = __builtin_nontemporal_load((const v4*)p);
    return make_int4(v.x, v.y, v.z, v.w);
}

// One-shot grid (r5 structure). Wave = 8 groups = 8 pairs = 16 edges.
// Cooperative idx fetch: lanes 0-7 load the wave's 8 src int2-pairs, lanes
// 8-15 the dst pairs; __shfl distributes. Stores paired as float2.
// Row gathers are NONTEMPORAL (this round's single change vs r9).
__global__ __launch_bounds__(256, 8)
void edge_kernel5(const int4* __restrict__ fd, const int4* __restrict__ fg,
                  const float* __restrict__ sd, const float* __restrict__ sg,
                  const int* __restrict__ src, const int* __restrict__ dst,
                  float* __restrict__ out, int n_edges)
{
    int npairs = (n_edges + 1) >> 1;
    int wl   = threadIdx.x & 63;
    int wid  = threadIdx.x >> 6;                    // wave in block (0..3)
    int gw   = wl >> 3;                             // group in wave (0..7)
    int lane = wl & 7;
    int wavebase = (int)blockIdx.x * 32 + wid * 8;  // pair idx of group 0

    // cooperative index load (lanes 0..15 only)
    int2 r = make_int2(0, 0);
    if (wl < 16) {
        int pl = wavebase + (wl & 7);
        if (pl < npairs) {
            if ((n_edges & 1) && (pl == npairs - 1)) {
                // odd tail: int2 .y would read 4B past the array
                int v = (wl < 8) ? src[pl * 2] : dst[pl * 2];
                r = make_int2(v, v);
            } else {
                r = (wl < 8) ? ((const int2*)src)[pl]
                             : ((const int2*)dst)[pl];
            }
        }
    }

    int pair = wavebase + gw;
    if (pair >= npairs) return;                     // lanes 0-15 stay active
    int e0 = pair * 2;                              //   whenever any group is
    bool has1 = (e0 + 1) < n_edges;

    int s0 = __shfl(r.x, gw);
    int s1 = __shfl(r.y, gw);
    int d0 = __shfl(r.x, 8 + gw);
    int d1 = __shfl(r.y, 8 + gw);
    if (!has1) { s1 = s0; d1 = d0; }

    int4 a0 = ntload(fd + (size_t)s0 * 8 + lane);
    int4 b0 = ntload(fg + (size_t)d0 * 8 + lane);
    int4 a1 = ntload(fd + (size_t)s1 * 8 + lane);
    int4 b1 = ntload(fg + (size_t)d1 * 8 + lane);

    int acc0 = dot4(a0.x, b0.x, dot4(a0.y, b0.y, dot4(a0.z, b0.z, dot4(a0.w, b0.w, 0))));
    int acc1 = dot4(a1.x, b1.x, dot4(a1.y, b1.y, dot4(a1.z, b1.z, dot4(a1.w, b1.w, 0))));

    acc0 += __shfl_xor(acc0, 4);
    acc0 += __shfl_xor(acc0, 2);
    acc0 += __shfl_xor(acc0, 1);
    acc1 += __shfl_xor(acc1, 4);
    acc1 += __shfl_xor(acc1, 2);
    acc1 += __shfl_xor(acc1, 1);

    if (lane == 0) {
        float r0 = (float)acc0 * sd[s0] * sg[d0];
        if (has1) {
            float r1 = (float)acc1 * sd[s1] * sg[d1];
            ((float2*)out)[pair] = make_float2(r0, r1);   // e0 even -> aligned
        } else {
            out[e0] = r0;
        }
    }
}

extern "C" void kernel_launch(void* const* d_in, const int* in_sizes, int n_in,
                              void* d_out, int out_size, void* d_ws, size_t ws_size,
                              hipStream_t stream) {
    const float* xd = (const float*)d_in[0];
    const float* hd = (const float*)d_in[1];
    const float* xg = (const float*)d_in[2];
    const float* hg = (const float*)d_in[3];
    const int*  src = (const int*)d_in[4];
    const int*  dst = (const int*)d_in[5];

    int n_d     = in_sizes[0] / FD;
    int n_g     = in_sizes[2] / FD;
    int n_edges = in_sizes[4];

    // ws layout: fd rows (n_d*128 B) | fg rows (n_g*128 B) | sd | sg
    char* ws = (char*)d_ws;
    int4*  fd = (int4*)ws;   ws += (size_t)n_d * 128;
    int4*  fg = (int4*)ws;   ws += (size_t)n_g * 128;
    float* sd = (float*)ws;  ws += (size_t)n_d * sizeof(float);
    float* sg = (float*)ws;
    float* out = (float*)d_out;

    int total_nodes = n_d + n_g;
    int nb1 = (total_nodes * 8 + 255) / 256;
    pack_kernel<<<nb1, 256, 0, stream>>>((const float4*)xd, (const float4*)hd,
                                         (const float4*)xg, (const float4*)hg,
                                         fd, fg, sd, sg, n_d, n_g);

    int npairs = (n_edges + 1) / 2;
    int nb2 = (npairs + 31) / 32;
    if (nb2 < 1) nb2 = 1;
    edge_kernel5<<<nb2, 256, 0, stream>>>(fd, fg, sd, sg, src, dst,
                                          out, n_edges);
}

// Round 15
// 162.112 us; speedup vs baseline: 1.2499x; 1.2499x over previous
//
#include <hip/hip_runtime.h>

// Round 11 (resubmit — GPUAcquisitionTimeout, never ran):
// revert nontemporal (r10: 59->100us, +13% FETCH — L1 merging is
// load-bearing; 7th and final null on the edge wall). Edge kernel closed at
// ~59us = 113% of the divergent-lane-rate floor (32M lane-loads/256CU/2.4GHz
// = 52us). Remaining headroom is PACK: 64MB streamed in ~30us = 2.1 TB/s
// (33% of BW) because 8-lane pack = 3125 waves vs 8192 slots (0.38x
// occupancy). Fix: 32 lanes/node (16 for x float4s, 16 for h, unit stride),
// 5-shuffle reduce, each lane quantizes its 4 floats -> one int store.
// 3.2M threads = 12.5K waves (1.5x oversub). Layout: linear (x bytes 0-63,
// h bytes 64-127) — consistent for fd and fg, dot invariant.
// Predict: pack 30->12-16us, edge 59 (unchanged), total ~142-147.

#define FD 64

__device__ __forceinline__ int q8pack(float v0, float v1, float v2, float v3, float inv) {
    float a0 = fminf(fmaxf(v0 * inv, -127.f), 127.f);
    float a1 = fminf(fmaxf(v1 * inv, -127.f), 127.f);
    float a2 = fminf(fmaxf(v2 * inv, -127.f), 127.f);
    float a3 = fminf(fmaxf(v3 * inv, -127.f), 127.f);
    int q0 = ((int)rintf(a0)) & 0xff;
    int q1 = ((int)rintf(a1)) & 0xff;
    int q2 = ((int)rintf(a2)) & 0xff;
    int q3 = ((int)rintf(a3)) & 0xff;
    return q0 | (q1 << 8) | (q2 << 16) | (q3 << 24);
}

// 32 lanes per node: lanes 0-15 load x float4[l], lanes 16-31 load h
// float4[l-16] (all unit-stride). Reduce ss/mx over 32 lanes (5 shuffles;
// 32-lane groups align within the 64-lane wave). Each lane stores one int
// (its 4 quantized values): row = 32 lanes x 4 B = 128 B linear layout.
__global__ __launch_bounds__(256, 8)
void pack_kernel(const float4* __restrict__ xd, const float4* __restrict__ hd,
                 const float4* __restrict__ xg, const float4* __restrict__ hg,
                 int* __restrict__ fd, int* __restrict__ fg,
                 float* __restrict__ sd, float* __restrict__ sg,
                 int n_d, int n_g)
{
    int tid  = (int)(blockIdx.x * blockDim.x + threadIdx.x);
    int node = tid >> 5;
    int sub  = threadIdx.x & 31;
    int total = n_d + n_g;
    if (node >= total) return;

    const float4* x; const float4* h; int* o; float* s; int n;
    if (node < n_d) { x = xd; h = hd; o = fd; s = sd; n = node; }
    else            { x = xg; h = hg; o = fg; s = sg; n = node - n_d; }

    int l = sub & 15;
    float4 v = (sub < 16) ? x[(size_t)n * 16 + l] : h[(size_t)n * 16 + l];

    float ss = v.x*v.x + v.y*v.y + v.z*v.z + v.w*v.w;
    #pragma unroll
    for (int m = 16; m >= 1; m >>= 1) ss += __shfl_xor(ss, m);
    float r = rsqrtf(ss);

    v.x *= r; v.y *= r; v.z *= r; v.w *= r;

    float mx = fmaxf(fmaxf(fabsf(v.x), fabsf(v.y)), fmaxf(fabsf(v.z), fabsf(v.w)));
    #pragma unroll
    for (int m = 16; m >= 1; m >>= 1) mx = fmaxf(mx, __shfl_xor(mx, m));

    float inv = 127.0f / mx;

    // linear layout: lane sub covers bytes [4*sub, 4*sub+4) of the 128B row
    o[(size_t)n * 32 + sub] = q8pack(v.x, v.y, v.z, v.w, inv);

    if (sub == 0) s[n] = mx * (1.0f / 127.0f);
}

__device__ __forceinline__ int dot4(int a, int b, int c) {
    return __builtin_amdgcn_sdot4(a, b, c, false);   // v_dot4_i32_i8
}

// One-shot grid (r9 proven form, plain loads). Wave = 8 groups = 8 pairs =
// 16 edges. Cooperative idx fetch: lanes 0-7 load the wave's 8 src
// int2-pairs, lanes 8-15 the dst pairs; __shfl distributes. float2 stores.
__global__ __launch_bounds__(256, 8)
void edge_kernel5(const int4* __restrict__ fd, const int4* __restrict__ fg,
                  const float* __restrict__ sd, const float* __restrict__ sg,
                  const int* __restrict__ src, const int* __restrict__ dst,
                  float* __restrict__ out, int n_edges)
{
    int npairs = (n_edges + 1) >> 1;
    int wl   = threadIdx.x & 63;
    int wid  = threadIdx.x >> 6;                    // wave in block (0..3)
    int gw   = wl >> 3;                             // group in wave (0..7)
    int lane = wl & 7;
    int wavebase = (int)blockIdx.x * 32 + wid * 8;  // pair idx of group 0

    // cooperative index load (lanes 0..15 only)
    int2 r = make_int2(0, 0);
    if (wl < 16) {
        int pl = wavebase + (wl & 7);
        if (pl < npairs) {
            if ((n_edges & 1) && (pl == npairs - 1)) {
                // odd tail: int2 .y would read 4B past the array
                int v = (wl < 8) ? src[pl * 2] : dst[pl * 2];
                r = make_int2(v, v);
            } else {
                r = (wl < 8) ? ((const int2*)src)[pl]
                             : ((const int2*)dst)[pl];
            }
        }
    }

    int pair = wavebase + gw;
    if (pair >= npairs) return;                     // lanes 0-15 stay active
    int e0 = pair * 2;                              //   whenever any group is
    bool has1 = (e0 + 1) < n_edges;

    int s0 = __shfl(r.x, gw);
    int s1 = __shfl(r.y, gw);
    int d0 = __shfl(r.x, 8 + gw);
    int d1 = __shfl(r.y, 8 + gw);
    if (!has1) { s1 = s0; d1 = d0; }

    int4 a0 = fd[(size_t)s0 * 8 + lane];
    int4 b0 = fg[(size_t)d0 * 8 + lane];
    int4 a1 = fd[(size_t)s1 * 8 + lane];
    int4 b1 = fg[(size_t)d1 * 8 + lane];

    int acc0 = dot4(a0.x, b0.x, dot4(a0.y, b0.y, dot4(a0.z, b0.z, dot4(a0.w, b0.w, 0))));
    int acc1 = dot4(a1.x, b1.x, dot4(a1.y, b1.y, dot4(a1.z, b1.z, dot4(a1.w, b1.w, 0))));

    acc0 += __shfl_xor(acc0, 4);
    acc0 += __shfl_xor(acc0, 2);
    acc0 += __shfl_xor(acc0, 1);
    acc1 += __shfl_xor(acc1, 4);
    acc1 += __shfl_xor(acc1, 2);
    acc1 += __shfl_xor(acc1, 1);

    if (lane == 0) {
        float r0 = (float)acc0 * sd[s0] * sg[d0];
        if (has1) {
            float r1 = (float)acc1 * sd[s1] * sg[d1];
            ((float2*)out)[pair] = make_float2(r0, r1);   // e0 even -> aligned
        } else {
            out[e0] = r0;
        }
    }
}

extern "C" void kernel_launch(void* const* d_in, const int* in_sizes, int n_in,
                              void* d_out, int out_size, void* d_ws, size_t ws_size,
                              hipStream_t stream) {
    const float* xd = (const float*)d_in[0];
    const float* hd = (const float*)d_in[1];
    const float* xg = (const float*)d_in[2];
    const float* hg = (const float*)d_in[3];
    const int*  src = (const int*)d_in[4];
    const int*  dst = (const int*)d_in[5];

    int n_d     = in_sizes[0] / FD;
    int n_g     = in_sizes[2] / FD;
    int n_edges = in_sizes[4];

    // ws layout: fd rows (n_d*128 B) | fg rows (n_g*128 B) | sd | sg
    char* ws = (char*)d_ws;
    int*   fd = (int*)ws;    ws += (size_t)n_d * 128;
    int*   fg = (int*)ws;    ws += (size_t)n_g * 128;
    float* sd = (float*)ws;  ws += (size_t)n_d * sizeof(float);
    float* sg = (float*)ws;
    float* out = (float*)d_out;

    int total_nodes = n_d + n_g;
    int nb1 = (total_nodes * 32 + 255) / 256;
    pack_kernel<<<nb1, 256, 0, stream>>>((const float4*)xd, (const float4*)hd,
                                         (const float4*)xg, (const float4*)hg,
                                         fd, fg, sd, sg, n_d, n_g);

    int npairs = (n_edges + 1) / 2;
    int nb2 = (npairs + 31) / 32;
    if (nb2 < 1) nb2 = 1;
    edge_kernel5<<<nb2, 256, 0, stream>>>((const int4*)fd, (const int4*)fg,
                                          sd, sg, src, dst, out, n_edges);
}

// Round 18
// 152.782 us; speedup vs baseline: 1.3262x; 1.0611x over previous
//
#include <hip/hip_runtime.h>

// Round 12 (resubmit #2 — GPUAcquisitionTimeout twice, never ran on HW):
// quantized-cosine denominator. r11: 4x occupancy on pack = NULL
// (pack ~30us invariant across 8/16/32-lane structures; ~70us is harness
// memset resets, untouchable). Edge ledger: per wave-iter (16 edges) 256
// row-gather lane-addrs + 32 divergent sd/sg scalar gathers (10%). Since
// pack normalizes rows pre-quantization, s ~= 1/||q||, so
// dot*s_d*s_g ~= sum(ab)/sqrt(sum(a^2)*sum(b^2)) — cosine of the QUANTIZED
// rows: 16 extra dot4 self-products + 4 extra reductions, ZERO loads.
// Removes sd/sg arrays + stores + 4M divergent loads. VALUBusy 29% -> ~50%,
// below wall. Pack reverted to r9-proven 8-lane form (158.4us best).
// Predict: edge 59->53-56, total ~152-156. Decision rule: edge >= 58 or
// absmax fail -> revert to exact r9, declare ROOFLINE.

#define FD 64

__device__ __forceinline__ int q8pack(float v0, float v1, float v2, float v3, float inv) {
    float a0 = fminf(fmaxf(v0 * inv, -127.f), 127.f);
    float a1 = fminf(fmaxf(v1 * inv, -127.f), 127.f);
    float a2 = fminf(fmaxf(v2 * inv, -127.f), 127.f);
    float a3 = fminf(fmaxf(v3 * inv, -127.f), 127.f);
    int q0 = ((int)rintf(a0)) & 0xff;
    int q1 = ((int)rintf(a1)) & 0xff;
    int q2 = ((int)rintf(a2)) & 0xff;
    int q3 = ((int)rintf(a3)) & 0xff;
    return q0 | (q1 << 8) | (q2 << 16) | (q3 << 24);
}

// 8 lanes per node (r9-proven). Lane l holds dims [8l, 8l+8) of x and h;
// writes one int4 (16 int8) -> row = 8 lanes x 16 B = 128 B.
// No scale array: the edge kernel reconstructs 1/||q|| from self-dots.
__global__ __launch_bounds__(256, 8)
void pack_kernel(const float4* __restrict__ xd, const float4* __restrict__ hd,
                 const float4* __restrict__ xg, const float4* __restrict__ hg,
                 int4* __restrict__ fd, int4* __restrict__ fg,
                 int n_d, int n_g)
{
    int tid  = (int)(blockIdx.x * blockDim.x + threadIdx.x);
    int node = tid >> 3;
    int lane = threadIdx.x & 7;
    int total = n_d + n_g;
    if (node >= total) return;

    const float4* x; const float4* h; int4* o; int n;
    if (node < n_d) { x = xd; h = hd; o = fd; n = node; }
    else            { x = xg; h = hg; o = fg; n = node - n_d; }

    float4 a0 = x[(size_t)n * 16 + lane * 2];
    float4 a1 = x[(size_t)n * 16 + lane * 2 + 1];
    float4 b0 = h[(size_t)n * 16 + lane * 2];
    float4 b1 = h[(size_t)n * 16 + lane * 2 + 1];

    float ss = a0.x*a0.x + a0.y*a0.y + a0.z*a0.z + a0.w*a0.w
             + a1.x*a1.x + a1.y*a1.y + a1.z*a1.z + a1.w*a1.w
             + b0.x*b0.x + b0.y*b0.y + b0.z*b0.z + b0.w*b0.w
             + b1.x*b1.x + b1.y*b1.y + b1.z*b1.z + b1.w*b1.w;
    #pragma unroll
    for (int m = 4; m >= 1; m >>= 1) ss += __shfl_xor(ss, m);
    float r = rsqrtf(ss);

    a0.x *= r; a0.y *= r; a0.z *= r; a0.w *= r;
    a1.x *= r; a1.y *= r; a1.z *= r; a1.w *= r;
    b0.x *= r; b0.y *= r; b0.z *= r; b0.w *= r;
    b1.x *= r; b1.y *= r; b1.z *= r; b1.w *= r;

    float mx = fmaxf(
        fmaxf(fmaxf(fmaxf(fabsf(a0.x), fabsf(a0.y)), fmaxf(fabsf(a0.z), fabsf(a0.w))),
              fmaxf(fmaxf(fabsf(a1.x), fabsf(a1.y)), fmaxf(fabsf(a1.z), fabsf(a1.w)))),
        fmaxf(fmaxf(fmaxf(fabsf(b0.x), fabsf(b0.y)), fmaxf(fabsf(b0.z), fabsf(b0.w))),
              fmaxf(fmaxf(fabsf(b1.x), fabsf(b1.y)), fmaxf(fabsf(b1.z), fabsf(b1.w)))));
    #pragma unroll
    for (int m = 4; m >= 1; m >>= 1) mx = fmaxf(mx, __shfl_xor(mx, m));

    float inv = 127.0f / mx;

    int4 w;
    w.x = q8pack(a0.x, a0.y, a0.z, a0.w, inv);
    w.y = q8pack(a1.x, a1.y, a1.z, a1.w, inv);
    w.z = q8pack(b0.x, b0.y, b0.z, b0.w, inv);
    w.w = q8pack(b1.x, b1.y, b1.z, b1.w, inv);
    o[(size_t)n * 8 + lane] = w;
}

__device__ __forceinline__ int dot4(int a, int b, int c) {
    return __builtin_amdgcn_sdot4(a, b, c, false);   // v_dot4_i32_i8
}

__device__ __forceinline__ int self4(int4 v) {
    return dot4(v.x, v.x, dot4(v.y, v.y, dot4(v.z, v.z, dot4(v.w, v.w, 0))));
}

__device__ __forceinline__ int red8(int v) {
    v += __shfl_xor(v, 4);
    v += __shfl_xor(v, 2);
    v += __shfl_xor(v, 1);
    return v;
}

// One-shot grid, r9 coop-idx structure. Wave = 8 groups = 8 pairs = 16
// edges. out = sum(ab) * rsqrt(sum(a^2)*sum(b^2)) — quantized cosine,
// no scale gathers.
__global__ __launch_bounds__(256, 8)
void edge_kernel6(const int4* __restrict__ fd, const int4* __restrict__ fg,
                  const int* __restrict__ src, const int* __restrict__ dst,
                  float* __restrict__ out, int n_edges)
{
    int npairs = (n_edges + 1) >> 1;
    int wl   = threadIdx.x & 63;
    int wid  = threadIdx.x >> 6;                    // wave in block (0..3)
    int gw   = wl >> 3;                             // group in wave (0..7)
    int lane = wl & 7;
    int wavebase = (int)blockIdx.x * 32 + wid * 8;  // pair idx of group 0

    // cooperative index load (lanes 0..15 only)
    int2 r = make_int2(0, 0);
    if (wl < 16) {
        int pl = wavebase + (wl & 7);
        if (pl < npairs) {
            if ((n_edges & 1) && (pl == npairs - 1)) {
                // odd tail: int2 .y would read 4B past the array
                int v = (wl < 8) ? src[pl * 2] : dst[pl * 2];
                r = make_int2(v, v);
            } else {
                r = (wl < 8) ? ((const int2*)src)[pl]
                             : ((const int2*)dst)[pl];
            }
        }
    }

    int pair = wavebase + gw;
    if (pair >= npairs) return;                     // lanes 0-15 stay active
    int e0 = pair * 2;                              //   whenever any group is
    bool has1 = (e0 + 1) < n_edges;

    int s0 = __shfl(r.x, gw);
    int s1 = __shfl(r.y, gw);
    int d0 = __shfl(r.x, 8 + gw);
    int d1 = __shfl(r.y, 8 + gw);
    if (!has1) { s1 = s0; d1 = d0; }

    int4 a0 = fd[(size_t)s0 * 8 + lane];
    int4 b0 = fg[(size_t)d0 * 8 + lane];
    int4 a1 = fd[(size_t)s1 * 8 + lane];
    int4 b1 = fg[(size_t)d1 * 8 + lane];

    int acc0 = dot4(a0.x, b0.x, dot4(a0.y, b0.y, dot4(a0.z, b0.z, dot4(a0.w, b0.w, 0))));
    int acc1 = dot4(a1.x, b1.x, dot4(a1.y, b1.y, dot4(a1.z, b1.z, dot4(a1.w, b1.w, 0))));
    int sa0  = self4(a0);
    int sb0  = self4(b0);
    int sa1  = self4(a1);
    int sb1  = self4(b1);

    acc0 = red8(acc0);
    acc1 = red8(acc1);
    sa0  = red8(sa0);
    sb0  = red8(sb0);
    sa1  = red8(sa1);
    sb1  = red8(sb1);

    if (lane == 0) {
        float r0 = (float)acc0 * rsqrtf((float)sa0 * (float)sb0);
        if (has1) {
            float r1 = (float)acc1 * rsqrtf((float)sa1 * (float)sb1);
            ((float2*)out)[pair] = make_float2(r0, r1);   // e0 even -> aligned
        } else {
            out[e0] = r0;
        }
    }
}

extern "C" void kernel_launch(void* const* d_in, const int* in_sizes, int n_in,
                              void* d_out, int out_size, void* d_ws, size_t ws_size,
                              hipStream_t stream) {
    const float* xd = (const float*)d_in[0];
    const float* hd = (const float*)d_in[1];
    const float* xg = (const float*)d_in[2];
    const float* hg = (const float*)d_in[3];
    const int*  src = (const int*)d_in[4];
    const int*  dst = (const int*)d_in[5];

    int n_d     = in_sizes[0] / FD;
    int n_g     = in_sizes[2] / FD;
    int n_edges = in_sizes[4];

    // ws layout: fd rows (n_d*128 B) | fg rows (n_g*128 B)
    char* ws = (char*)d_ws;
    int4*  fd = (int4*)ws;   ws += (size_t)n_d * 128;
    int4*  fg = (int4*)ws;
    float* out = (float*)d_out;

    int total_nodes = n_d + n_g;
    int nb1 = (total_nodes * 8 + 255) / 256;
    pack_kernel<<<nb1, 256, 0, stream>>>((const float4*)xd, (const float4*)hd,
                                         (const float4*)xg, (const float4*)hg,
                                         fd, fg, n_d, n_g);

    int npairs = (n_edges + 1) / 2;
    int nb2 = (npairs + 31) / 32;
    if (nb2 < 1) nb2 = 1;
    edge_kernel6<<<nb2, 256, 0, stream>>>(fd, fg, src, dst, out, n_edges);
}